// Round 14
// baseline (76.744 us; speedup 1.0000x reference)
//
#include <hip/hip_runtime.h>

#define N_NODES 50000
#define N_EDGES 1600000
#define D 64
#define CAP 96                                  // deg ~ Poisson(32); P(>=96) ~ 0
#define CHUNK 4096
#define NCHUNK ((N_EDGES + CHUNK - 1) / CHUNK)  // 391
#define NBUCK 196                               // dst>>8; max 49999>>8 = 195
#define DUMMY 0xFFFF                            // dummy adj index -> zero row
#define NROWS 65536                             // hf2 rows (row 65535 = zeros)
#define G_LNB 12500                             // LN blocks (50000*64/256)
#define G_HIST0 (G_LNB + 1)                     // hist blocks start (12501)
#define G_FILL0 (G_HIST0 + NCHUNK)              // fill blocks start (12892)
#define ADJ_U4 (N_NODES * CAP * 2 / 16)         // 600000 uint4 in adj
#define FILLB ((ADJ_U4 + 1023) / 1024)          // 586 fill blocks

typedef _Float16 f16x2 __attribute__((ext_vector_type(2)));

static __device__ __forceinline__ float dot2acc(f16x2 a, f16x2 b, float c) {
#if __has_builtin(__builtin_amdgcn_fdot2)
  return __builtin_amdgcn_fdot2(a, b, c, false);
#else
  return c + (float)a.x * (float)b.x + (float)a.y * (float)b.y;
#endif
}

static __device__ __forceinline__ f16x2 shflx2(f16x2 v, int msk) {
  return __builtin_bit_cast(
      f16x2, (unsigned)__shfl_xor((int)__builtin_bit_cast(unsigned, v), msk, 64));
}

static __device__ __forceinline__ f16x2 bc2(unsigned u) {
  return __builtin_bit_cast(f16x2, u);
}

// 32-slot (per node) gather for two nodes: 8 row-loads issued before any
// accumulate; packed-f16 accumulation. Dummy lanes hit the L1-hot zero row.
static __device__ __forceinline__ void gpair(
    int myA, int myB, int off, int o, const char* hb, int coff,
    f16x2* aA, f16x2* aB) {
  uint4 va[4], vb[4];
#pragma unroll
  for (int j = 0; j < 4; ++j) {
    int ia = __shfl(myA, off + j * 8 + o, 64);
    va[j] = *(const uint4*)(hb + ((ia << 7) | coff));
  }
#pragma unroll
  for (int j = 0; j < 4; ++j) {
    int ib = __shfl(myB, off + j * 8 + o, 64);
    vb[j] = *(const uint4*)(hb + ((ib << 7) | coff));
  }
#pragma unroll
  for (int j = 0; j < 4; ++j) {
    aA[0] += bc2(va[j].x);
    aA[1] += bc2(va[j].y);
    aA[2] += bc2(va[j].z);
    aA[3] += bc2(va[j].w);
    aB[0] += bc2(vb[j].x);
    aB[1] += bc2(vb[j].y);
    aB[2] += bc2(vb[j].z);
    aB[3] += bc2(vb[j].w);
  }
}

// Deep path: all 64 slots for both nodes, ALL 16 row-loads issued before any
// accumulate (one exposed round trip instead of two). Used only when the
// ballot says slots 32-63 contain real edges.
static __device__ __forceinline__ void g64(
    int myA, int myB, int o, const char* hb, int coff, f16x2* aA, f16x2* aB) {
  uint4 va[8], vb[8];
#pragma unroll
  for (int j = 0; j < 8; ++j) {
    int ia = __shfl(myA, j * 8 + o, 64);
    va[j] = *(const uint4*)(hb + ((ia << 7) | coff));
  }
#pragma unroll
  for (int j = 0; j < 8; ++j) {
    int ib = __shfl(myB, j * 8 + o, 64);
    vb[j] = *(const uint4*)(hb + ((ib << 7) | coff));
  }
#pragma unroll
  for (int j = 0; j < 8; ++j) {
    aA[0] += bc2(va[j].x);
    aA[1] += bc2(va[j].y);
    aA[2] += bc2(va[j].z);
    aA[3] += bc2(va[j].w);
    aB[0] += bc2(vb[j].x);
    aB[1] += bc2(vb[j].y);
    aB[2] += bc2(vb[j].z);
    aB[3] += bc2(vb[j].w);
  }
}

// Kernel 1 (fused, all-independent parts):
//   blocks [0,12500): LayerNorm+ReLU+mask -> f16 rows (128 B) of hf2
//   block  12500    : zero row DUMMY (65535)
//   blocks [12501,12892): per-chunk histogram over 196 buckets (dst>>8)
//   blocks [12892,13478): fill adj with DUMMY (0xFFFF bytes, uint4 stores)
__global__ __launch_bounds__(256) void k_front(
    const float* __restrict__ x, const float* __restrict__ mask,
    const float* __restrict__ gamma, const float* __restrict__ beta,
    f16x2* __restrict__ hf2, const int* __restrict__ ei,
    int* __restrict__ ghistT, uint4* __restrict__ adj4) {
  __shared__ int lhist[NBUCK];
  int b = blockIdx.x;
  if (b >= G_FILL0) {  // adj dummy-fill
    int base = (b - G_FILL0) * 1024;
    uint4 f;
    f.x = f.y = f.z = f.w = 0xFFFFFFFFu;
#pragma unroll
    for (int j = 0; j < 4; ++j) {
      int i = base + j * 256 + threadIdx.x;
      if (i < ADJ_U4) adj4[i] = f;
    }
    return;
  }
  if (b >= G_HIST0) {  // histogram
    int base = (b - G_HIST0) * CHUNK;
    int len = min(CHUNK, N_EDGES - base);  // multiple of 4
    for (int i = threadIdx.x; i < NBUCK; i += 256) lhist[i] = 0;
    __syncthreads();
    const int4* pd = (const int4*)(ei + N_EDGES + base);
    for (int i = threadIdx.x; i < (len >> 2); i += 256) {
      int4 v = pd[i];
      atomicAdd(&lhist[((unsigned)v.x) >> 8], 1);
      atomicAdd(&lhist[((unsigned)v.y) >> 8], 1);
      atomicAdd(&lhist[((unsigned)v.z) >> 8], 1);
      atomicAdd(&lhist[((unsigned)v.w) >> 8], 1);
    }
    __syncthreads();
    for (int k = threadIdx.x; k < NBUCK; k += 256)
      ghistT[k * NCHUNK + (b - G_HIST0)] = lhist[k];
    return;
  }
  if (b == G_LNB) {  // zero row
    if (threadIdx.x < 32) {
      f16x2 z;
      z.x = (_Float16)0.f;
      z.y = (_Float16)0.f;
      hf2[(size_t)DUMMY * 32 + threadIdx.x] = z;
    }
    return;
  }
  // LayerNorm part: 4 nodes/block
  int tid = b * 256 + threadIdx.x;
  int n = tid >> 6;
  int d = tid & 63;
  float v = x[n * D + d];
  float s = v, s2 = v * v;
#pragma unroll
  for (int off = 32; off >= 1; off >>= 1) {
    s += __shfl_xor(s, off, 64);
    s2 += __shfl_xor(s2, off, 64);
  }
  float mu = s * (1.0f / D);
  float var = fmaxf(s2 * (1.0f / D) - mu * mu, 0.0f);
  float hv = (v - mu) * rsqrtf(var + 1e-5f) * gamma[d] + beta[d];
  hv = fmaxf(hv, 0.0f) * mask[n * D + d];
  float hn = __shfl_xor(hv, 1, 64);
  if ((d & 1) == 0) {
    f16x2 p;
    p.x = (_Float16)hv;
    p.y = (_Float16)hn;
    hf2[(size_t)n * 32 + (d >> 1)] = p;
  }
}

// Kernel 2a: per-bucket exclusive scan over 391 chunk counts + bucket total.
__global__ __launch_bounds__(256) void k_scan1(
    const int* __restrict__ ghistT, int* __restrict__ chunkbaseT,
    int* __restrict__ total) {
  __shared__ int sbuf[2][512];
  int k = blockIdx.x;
  int t = threadIdx.x;
  int v0 = (t < NCHUNK) ? ghistT[k * NCHUNK + t] : 0;
  int v1 = (t + 256 < NCHUNK) ? ghistT[k * NCHUNK + t + 256] : 0;
  sbuf[0][t] = v0;
  sbuf[0][t + 256] = v1;
  __syncthreads();
  int cur = 0;
#pragma unroll
  for (int off = 1; off < 512; off <<= 1) {
    int a0 = sbuf[cur][t] + ((t >= off) ? sbuf[cur][t - off] : 0);
    int a1 = sbuf[cur][t + 256] + ((t + 256 >= off) ? sbuf[cur][t + 256 - off] : 0);
    sbuf[cur ^ 1][t] = a0;
    sbuf[cur ^ 1][t + 256] = a1;
    __syncthreads();
    cur ^= 1;
  }
  if (t < NCHUNK) chunkbaseT[k * NCHUNK + t] = sbuf[cur][t] - v0;
  if (t + 256 < NCHUNK) chunkbaseT[k * NCHUNK + t + 256] = sbuf[cur][t + 256] - v1;
  if (t == 0) total[k] = sbuf[cur][NCHUNK - 1];
}

// Kernel 2b: block 0: exclusive scan of 196 bucket totals. Blocks 1..16:
// convert Wl,Wr (fp32) to packed f16 (independent work, fused here).
__global__ __launch_bounds__(256) void k_scan2(
    const int* __restrict__ total, int* __restrict__ bucket_start,
    const float* __restrict__ Wl, const float* __restrict__ Wr,
    f16x2* __restrict__ wf16) {
  if (blockIdx.x > 0) {
    int g = (blockIdx.x - 1) * 256 + threadIdx.x;  // 0..4095
    float2 v = (g < 2048) ? ((const float2*)Wl)[g] : ((const float2*)Wr)[g - 2048];
    f16x2 p;
    p.x = (_Float16)v.x;
    p.y = (_Float16)v.y;
    wf16[g] = p;
    return;
  }
  __shared__ int sbuf[2][256];
  int t = threadIdx.x;
  int v = (t < NBUCK) ? total[t] : 0;
  sbuf[0][t] = v;
  __syncthreads();
  int cur = 0;
#pragma unroll
  for (int off = 1; off < 256; off <<= 1) {
    int a = sbuf[cur][t] + ((t >= off) ? sbuf[cur][t - off] : 0);
    sbuf[cur ^ 1][t] = a;
    __syncthreads();
    cur ^= 1;
  }
  if (t < NBUCK) bucket_start[t] = sbuf[cur][t] - v;
  if (t == 0) bucket_start[NBUCK] = N_EDGES;
}

// Kernel 3: scatter records into bucket-sorted order via per-bucket LDS
// cursors; int4 edge loads; 512 threads for latency hiding.
__global__ __launch_bounds__(512) void k_scatter2(
    const int* __restrict__ ei, const int* __restrict__ chunkbaseT,
    const int* __restrict__ bucket_start, unsigned* __restrict__ sorted) {
  __shared__ int lcur[NBUCK];
  int b = blockIdx.x;
  int base = b * CHUNK;
  int len = min(CHUNK, N_EDGES - base);  // multiple of 4
  for (int k = threadIdx.x; k < NBUCK; k += 512)
    lcur[k] = bucket_start[k] + chunkbaseT[k * NCHUNK + b];
  __syncthreads();
  const int4* ps = (const int4*)(ei + base);
  const int4* pd = (const int4*)(ei + N_EDGES + base);
  for (int i = threadIdx.x; i < (len >> 2); i += 512) {
    int4 s4 = ps[i];
    int4 d4 = pd[i];
    {
      unsigned dst = (unsigned)d4.x, src = (unsigned)s4.x;
      int pos = atomicAdd(&lcur[dst >> 8], 1);
      sorted[pos] = (dst << 16) | src;
    }
    {
      unsigned dst = (unsigned)d4.y, src = (unsigned)s4.y;
      int pos = atomicAdd(&lcur[dst >> 8], 1);
      sorted[pos] = (dst << 16) | src;
    }
    {
      unsigned dst = (unsigned)d4.z, src = (unsigned)s4.z;
      int pos = atomicAdd(&lcur[dst >> 8], 1);
      sorted[pos] = (dst << 16) | src;
    }
    {
      unsigned dst = (unsigned)d4.w, src = (unsigned)s4.w;
      int pos = atomicAdd(&lcur[dst >> 8], 1);
      sorted[pos] = (dst << 16) | src;
    }
  }
}

// Kernel 4: one 1024-thread block per 256-node bucket; stream the contiguous
// bucket region, place src (u16) into adj rows via LDS counters; write
// invd = 1/max(deg,1). No padding needed (adj pre-filled with DUMMY).
__global__ __launch_bounds__(1024) void k_place3(
    const unsigned* __restrict__ sorted, const int* __restrict__ bucket_start,
    unsigned short* __restrict__ adj, float* __restrict__ invd) {
  __shared__ int lcnt[256];
  int k = blockIdx.x;
  if (threadIdx.x < 256) lcnt[threadIdx.x] = 0;
  __syncthreads();
  int s = bucket_start[k];
  int e = bucket_start[k + 1];
  for (int i = s + threadIdx.x; i < e; i += 1024) {
    unsigned rec = sorted[i];
    int dst = (int)(rec >> 16);
    int pos = atomicAdd(&lcnt[dst & 255], 1);
    if (pos < CAP) adj[(size_t)dst * CAP + pos] = (unsigned short)(rec & 0xffffu);
  }
  __syncthreads();
  if (threadIdx.x < 256) {
    int dst = (k << 8) + threadIdx.x;
    if (dst < N_NODES)
      invd[dst] = 1.0f / (float)max(min(lcnt[threadIdx.x], CAP), 1);
  }
}

// Kernel 5: gather-mean + fused output matmuls. 512 threads = 8 waves; each
// wave owns TWO nodes. adj blind-loaded (dummy-padded). NEW: when the ballot
// shows real edges in slots 32-63, ALL 16 row-loads are issued before any
// accumulate (deep path) -> one exposed round trip instead of two.
__global__ __launch_bounds__(512, 5) void k_gather_out(
    const f16x2* __restrict__ hf2, const float* __restrict__ invd,
    const unsigned short* __restrict__ adj, const f16x2* __restrict__ wf16,
    const float* __restrict__ bl, float* __restrict__ out) {
  __shared__ f16x2 sWl2[D][34];
  __shared__ f16x2 sWr2[D][34];
  __shared__ f16x2 sA2[16][32];
  __shared__ f16x2 sH2[16][32];
  int w = threadIdx.x >> 6;
  int L = threadIdx.x & 63;
  {
    int i0 = threadIdx.x * 4;  // 4 consecutive words, same row
    int row = i0 >> 5, col = i0 & 31;
    const f16x2* wl = wf16;
    const f16x2* wr = wf16 + 2048;
#pragma unroll
    for (int j = 0; j < 4; ++j) {
      sWl2[row][col + j] = wl[i0 + j];
      sWr2[row][col + j] = wr[i0 + j];
    }
  }
  __syncthreads();

  int nA = blockIdx.x * 16 + w * 2;  // 50000 % 16 == 0
  int nB = nA + 1;
  int abA = nA * CAP, abB = nB * CAP;
  // independent loads, one round trip
  int myA = (int)__builtin_nontemporal_load(adj + abA + L);
  int myB = (int)__builtin_nontemporal_load(adj + abB + L);
  float invA = __builtin_nontemporal_load(invd + nA);
  float invB = __builtin_nontemporal_load(invd + nB);

  unsigned long long bm =
      __ballot(myA != DUMMY) | __ballot(myB != DUMMY);

  int o = L >> 3;
  int c8 = L & 7;
  int coff = c8 << 4;
  const char* hb = (const char*)hf2;

  f16x2 aA[4], aB[4];
#pragma unroll
  for (int t = 0; t < 4; ++t) {
    aA[t] = bc2(0u);
    aB[t] = bc2(0u);
  }
  if ((bm >> 32) != 0ull) {
    g64(myA, myB, o, hb, coff, aA, aB);   // deep: slots 0-63, 16 loads upfront
  } else {
    gpair(myA, myB, 0, o, hb, coff, aA, aB);  // shallow: slots 0-31 only
  }
  if ((bm >> 63) != 0ull) {  // rare: deg >= 64 -> slots 64-95 (dummy-padded)
    int myA2 = (L < 32) ? (int)__builtin_nontemporal_load(adj + abA + 64 + L)
                        : DUMMY;
    int myB2 = (L < 32) ? (int)__builtin_nontemporal_load(adj + abB + 64 + L)
                        : DUMMY;
    gpair(myA2, myB2, 0, o, hb, coff, aA, aB);
  }

  // combine the 8 lane-octants (bits 3,4,5 of L), packed f16
#pragma unroll
  for (int msk = 8; msk <= 32; msk <<= 1) {
#pragma unroll
    for (int t = 0; t < 4; ++t) {
      aA[t] += shflx2(aA[t], msk);
      aB[t] += shflx2(aB[t], msk);
    }
  }
  if (o == 0) {  // lane c8 owns features 8c8..8c8+7 of node A
#pragma unroll
    for (int t = 0; t < 4; ++t) {
      f16x2 p;
      p.x = (_Float16)((float)aA[t].x * invA);
      p.y = (_Float16)((float)aA[t].y * invA);
      sA2[2 * w][4 * c8 + t] = p;
    }
  } else if (o == 1) {  // node B (sums replicated across octants)
#pragma unroll
    for (int t = 0; t < 4; ++t) {
      f16x2 p;
      p.x = (_Float16)((float)aB[t].x * invB);
      p.y = (_Float16)((float)aB[t].y * invB);
      sA2[2 * w + 1][4 * c8 + t] = p;
    }
  }
  if (L < 32) sH2[2 * w][L] = hf2[(size_t)nA * 32 + L];
  else sH2[2 * w + 1][L - 32] = hf2[(size_t)nB * 32 + (L - 32)];

  float accA = bl[L];  // wave-private sA2/sH2: in-wave lgkmcnt ordering
  float accB = accA;
#pragma unroll
  for (int k2 = 0; k2 < 32; ++k2) {
    f16x2 wlv = sWl2[L][k2];
    f16x2 wrv = sWr2[L][k2];
    accA = dot2acc(sA2[2 * w][k2], wlv, accA);
    accA = dot2acc(sH2[2 * w][k2], wrv, accA);
    accB = dot2acc(sA2[2 * w + 1][k2], wlv, accB);
    accB = dot2acc(sH2[2 * w + 1][k2], wrv, accB);
  }
  __builtin_nontemporal_store(accA, out + (size_t)nA * D + L);
  __builtin_nontemporal_store(accB, out + (size_t)nB * D + L);
}

extern "C" void kernel_launch(void* const* d_in, const int* in_sizes, int n_in,
                              void* d_out, int out_size, void* d_ws,
                              size_t ws_size, hipStream_t stream) {
  const float* x = (const float*)d_in[0];
  const float* mask = (const float*)d_in[1];
  const float* gamma = (const float*)d_in[2];
  const float* beta = (const float*)d_in[3];
  const float* Wl = (const float*)d_in[4];
  const float* bl = (const float*)d_in[5];
  const float* Wr = (const float*)d_in[6];
  const int* ei = (const int*)d_in[7];
  float* out = (float*)d_out;

  // ws layout (~25.3 MB)
  f16x2* hf2 = (f16x2*)d_ws;                           // 65536*128 B = 8.39 MB
  unsigned* sorted = (unsigned*)(hf2 + (size_t)NROWS * 32);  // 6.4 MB
  int* ghistT = (int*)(sorted + (size_t)N_EDGES);      // 0.31 MB
  int* chunkbaseT = ghistT + NBUCK * NCHUNK;           // 0.31 MB
  int* total = chunkbaseT + NBUCK * NCHUNK;            // 0.8 KB
  int* bucket_start = total + NBUCK;                   // 0.8 KB
  float* invd = (float*)(bucket_start + (NBUCK + 2));  // 0.2 MB
  unsigned short* adj = (unsigned short*)(invd + N_NODES);  // 9.6 MB
  f16x2* wf16 = (f16x2*)(adj + (size_t)N_NODES * CAP);      // 16 KB

  dim3 blk(256);
  k_front<<<G_FILL0 + FILLB, blk, 0, stream>>>(x, mask, gamma, beta, hf2, ei,
                                               ghistT, (uint4*)adj);
  k_scan1<<<NBUCK, blk, 0, stream>>>(ghistT, chunkbaseT, total);
  k_scan2<<<17, blk, 0, stream>>>(total, bucket_start, Wl, Wr, wf16);
  k_scatter2<<<NCHUNK, dim3(512), 0, stream>>>(ei, chunkbaseT, bucket_start,
                                               sorted);
  k_place3<<<NBUCK, dim3(1024), 0, stream>>>(sorted, bucket_start, adj, invd);
  k_gather_out<<<N_NODES / 16, dim3(512), 0, stream>>>(hf2, invd, adj, wf16,
                                                       bl, out);
}

// Round 15
// 74.752 us; speedup vs baseline: 1.0266x; 1.0266x over previous
//
#include <hip/hip_runtime.h>

#define N_NODES 50000
#define N_EDGES 1600000
#define D 64
#define CAP 96                                  // deg ~ Poisson(32); P(>=96) ~ 0
#define CHUNK 4096
#define NCHUNK ((N_EDGES + CHUNK - 1) / CHUNK)  // 391
#define NBUCK 196                               // dst>>8; max 49999>>8 = 195
#define DUMMY 0xFFFF                            // dummy adj index -> zero row
#define NROWS 65536                             // hf2 rows (row 65535 = zeros)
#define G_LNB 12500                             // LN blocks (50000*64/256)
#define G_HIST0 (G_LNB + 1)                     // hist blocks start (12501)
#define G_FILL0 (G_HIST0 + NCHUNK)              // fill blocks start (12892)
#define ADJ_U4 (N_NODES * CAP * 2 / 16)         // 600000 uint4 in adj
#define FILLB ((ADJ_U4 + 1023) / 1024)          // 586 fill blocks

typedef _Float16 f16x2 __attribute__((ext_vector_type(2)));

static __device__ __forceinline__ float dot2acc(f16x2 a, f16x2 b, float c) {
#if __has_builtin(__builtin_amdgcn_fdot2)
  return __builtin_amdgcn_fdot2(a, b, c, false);
#else
  return c + (float)a.x * (float)b.x + (float)a.y * (float)b.y;
#endif
}

static __device__ __forceinline__ f16x2 shflx2(f16x2 v, int msk) {
  return __builtin_bit_cast(
      f16x2, (unsigned)__shfl_xor((int)__builtin_bit_cast(unsigned, v), msk, 64));
}

// Gather 32 edges for EACH of two nodes: issue all 8 row-loads (4 per node)
// before any accumulate; accumulate with packed f16 adds (v_pk_add_f16).
// Dummy lanes point at the zero row (cache-hot).
static __device__ __forceinline__ void gpair(
    int myA, int myB, int off, int o, const char* hb, int coff,
    f16x2* aA, f16x2* aB) {
  uint4 va[4], vb[4];
#pragma unroll
  for (int j = 0; j < 4; ++j) {
    int ia = __shfl(myA, off + j * 8 + o, 64);
    va[j] = *(const uint4*)(hb + ((ia << 7) | coff));
  }
#pragma unroll
  for (int j = 0; j < 4; ++j) {
    int ib = __shfl(myB, off + j * 8 + o, 64);
    vb[j] = *(const uint4*)(hb + ((ib << 7) | coff));
  }
#pragma unroll
  for (int j = 0; j < 4; ++j) {
    aA[0] += __builtin_bit_cast(f16x2, va[j].x);
    aA[1] += __builtin_bit_cast(f16x2, va[j].y);
    aA[2] += __builtin_bit_cast(f16x2, va[j].z);
    aA[3] += __builtin_bit_cast(f16x2, va[j].w);
    aB[0] += __builtin_bit_cast(f16x2, vb[j].x);
    aB[1] += __builtin_bit_cast(f16x2, vb[j].y);
    aB[2] += __builtin_bit_cast(f16x2, vb[j].z);
    aB[3] += __builtin_bit_cast(f16x2, vb[j].w);
  }
}

// Kernel 1 (fused, all-independent parts):
//   blocks [0,12500): LayerNorm+ReLU+mask -> f16 rows (128 B) of hf2
//   block  12500    : zero row DUMMY (65535)
//   blocks [12501,12892): per-chunk histogram over 196 buckets (dst>>8)
//   blocks [12892,13478): fill adj with DUMMY (0xFFFF bytes, uint4 stores)
__global__ __launch_bounds__(256) void k_front(
    const float* __restrict__ x, const float* __restrict__ mask,
    const float* __restrict__ gamma, const float* __restrict__ beta,
    f16x2* __restrict__ hf2, const int* __restrict__ ei,
    int* __restrict__ ghistT, uint4* __restrict__ adj4) {
  __shared__ int lhist[NBUCK];
  int b = blockIdx.x;
  if (b >= G_FILL0) {  // adj dummy-fill
    int base = (b - G_FILL0) * 1024;
    uint4 f;
    f.x = f.y = f.z = f.w = 0xFFFFFFFFu;
#pragma unroll
    for (int j = 0; j < 4; ++j) {
      int i = base + j * 256 + threadIdx.x;
      if (i < ADJ_U4) adj4[i] = f;
    }
    return;
  }
  if (b >= G_HIST0) {  // histogram
    int base = (b - G_HIST0) * CHUNK;
    int len = min(CHUNK, N_EDGES - base);  // multiple of 4
    for (int i = threadIdx.x; i < NBUCK; i += 256) lhist[i] = 0;
    __syncthreads();
    const int4* pd = (const int4*)(ei + N_EDGES + base);
    for (int i = threadIdx.x; i < (len >> 2); i += 256) {
      int4 v = pd[i];
      atomicAdd(&lhist[((unsigned)v.x) >> 8], 1);
      atomicAdd(&lhist[((unsigned)v.y) >> 8], 1);
      atomicAdd(&lhist[((unsigned)v.z) >> 8], 1);
      atomicAdd(&lhist[((unsigned)v.w) >> 8], 1);
    }
    __syncthreads();
    for (int k = threadIdx.x; k < NBUCK; k += 256)
      ghistT[k * NCHUNK + (b - G_HIST0)] = lhist[k];
    return;
  }
  if (b == G_LNB) {  // zero row
    if (threadIdx.x < 32) {
      f16x2 z;
      z.x = (_Float16)0.f;
      z.y = (_Float16)0.f;
      hf2[(size_t)DUMMY * 32 + threadIdx.x] = z;
    }
    return;
  }
  // LayerNorm part: 4 nodes/block
  int tid = b * 256 + threadIdx.x;
  int n = tid >> 6;
  int d = tid & 63;
  float v = x[n * D + d];
  float s = v, s2 = v * v;
#pragma unroll
  for (int off = 32; off >= 1; off >>= 1) {
    s += __shfl_xor(s, off, 64);
    s2 += __shfl_xor(s2, off, 64);
  }
  float mu = s * (1.0f / D);
  float var = fmaxf(s2 * (1.0f / D) - mu * mu, 0.0f);
  float hv = (v - mu) * rsqrtf(var + 1e-5f) * gamma[d] + beta[d];
  hv = fmaxf(hv, 0.0f) * mask[n * D + d];
  float hn = __shfl_xor(hv, 1, 64);
  if ((d & 1) == 0) {
    f16x2 p;
    p.x = (_Float16)hv;
    p.y = (_Float16)hn;
    hf2[(size_t)n * 32 + (d >> 1)] = p;
  }
}

// Kernel 2a: per-bucket exclusive scan over 391 chunk counts + bucket total.
__global__ __launch_bounds__(256) void k_scan1(
    const int* __restrict__ ghistT, int* __restrict__ chunkbaseT,
    int* __restrict__ total) {
  __shared__ int sbuf[2][512];
  int k = blockIdx.x;
  int t = threadIdx.x;
  int v0 = (t < NCHUNK) ? ghistT[k * NCHUNK + t] : 0;
  int v1 = (t + 256 < NCHUNK) ? ghistT[k * NCHUNK + t + 256] : 0;
  sbuf[0][t] = v0;
  sbuf[0][t + 256] = v1;
  __syncthreads();
  int cur = 0;
#pragma unroll
  for (int off = 1; off < 512; off <<= 1) {
    int a0 = sbuf[cur][t] + ((t >= off) ? sbuf[cur][t - off] : 0);
    int a1 = sbuf[cur][t + 256] + ((t + 256 >= off) ? sbuf[cur][t + 256 - off] : 0);
    sbuf[cur ^ 1][t] = a0;
    sbuf[cur ^ 1][t + 256] = a1;
    __syncthreads();
    cur ^= 1;
  }
  if (t < NCHUNK) chunkbaseT[k * NCHUNK + t] = sbuf[cur][t] - v0;
  if (t + 256 < NCHUNK) chunkbaseT[k * NCHUNK + t + 256] = sbuf[cur][t + 256] - v1;
  if (t == 0) total[k] = sbuf[cur][NCHUNK - 1];
}

// Kernel 2b: block 0: exclusive scan of 196 bucket totals. Blocks 1..16:
// convert Wl,Wr (fp32) to packed f16 (independent work, fused here).
__global__ __launch_bounds__(256) void k_scan2(
    const int* __restrict__ total, int* __restrict__ bucket_start,
    const float* __restrict__ Wl, const float* __restrict__ Wr,
    f16x2* __restrict__ wf16) {
  if (blockIdx.x > 0) {
    int g = (blockIdx.x - 1) * 256 + threadIdx.x;  // 0..4095
    float2 v = (g < 2048) ? ((const float2*)Wl)[g] : ((const float2*)Wr)[g - 2048];
    f16x2 p;
    p.x = (_Float16)v.x;
    p.y = (_Float16)v.y;
    wf16[g] = p;
    return;
  }
  __shared__ int sbuf[2][256];
  int t = threadIdx.x;
  int v = (t < NBUCK) ? total[t] : 0;
  sbuf[0][t] = v;
  __syncthreads();
  int cur = 0;
#pragma unroll
  for (int off = 1; off < 256; off <<= 1) {
    int a = sbuf[cur][t] + ((t >= off) ? sbuf[cur][t - off] : 0);
    sbuf[cur ^ 1][t] = a;
    __syncthreads();
    cur ^= 1;
  }
  if (t < NBUCK) bucket_start[t] = sbuf[cur][t] - v;
  if (t == 0) bucket_start[NBUCK] = N_EDGES;
}

// Kernel 3: scatter records into bucket-sorted order via per-bucket LDS
// cursors; int4 edge loads; 512 threads for latency hiding.
__global__ __launch_bounds__(512) void k_scatter2(
    const int* __restrict__ ei, const int* __restrict__ chunkbaseT,
    const int* __restrict__ bucket_start, unsigned* __restrict__ sorted) {
  __shared__ int lcur[NBUCK];
  int b = blockIdx.x;
  int base = b * CHUNK;
  int len = min(CHUNK, N_EDGES - base);  // multiple of 4
  for (int k = threadIdx.x; k < NBUCK; k += 512)
    lcur[k] = bucket_start[k] + chunkbaseT[k * NCHUNK + b];
  __syncthreads();
  const int4* ps = (const int4*)(ei + base);
  const int4* pd = (const int4*)(ei + N_EDGES + base);
  for (int i = threadIdx.x; i < (len >> 2); i += 512) {
    int4 s4 = ps[i];
    int4 d4 = pd[i];
    {
      unsigned dst = (unsigned)d4.x, src = (unsigned)s4.x;
      int pos = atomicAdd(&lcur[dst >> 8], 1);
      sorted[pos] = (dst << 16) | src;
    }
    {
      unsigned dst = (unsigned)d4.y, src = (unsigned)s4.y;
      int pos = atomicAdd(&lcur[dst >> 8], 1);
      sorted[pos] = (dst << 16) | src;
    }
    {
      unsigned dst = (unsigned)d4.z, src = (unsigned)s4.z;
      int pos = atomicAdd(&lcur[dst >> 8], 1);
      sorted[pos] = (dst << 16) | src;
    }
    {
      unsigned dst = (unsigned)d4.w, src = (unsigned)s4.w;
      int pos = atomicAdd(&lcur[dst >> 8], 1);
      sorted[pos] = (dst << 16) | src;
    }
  }
}

// Kernel 4: one 1024-thread block per 256-node bucket; stream the contiguous
// bucket region, place src (u16) into adj rows via LDS counters; write
// invd = 1/max(deg,1). No padding needed (adj pre-filled with DUMMY).
__global__ __launch_bounds__(1024) void k_place3(
    const unsigned* __restrict__ sorted, const int* __restrict__ bucket_start,
    unsigned short* __restrict__ adj, float* __restrict__ invd) {
  __shared__ int lcnt[256];
  int k = blockIdx.x;
  if (threadIdx.x < 256) lcnt[threadIdx.x] = 0;
  __syncthreads();
  int s = bucket_start[k];
  int e = bucket_start[k + 1];
  for (int i = s + threadIdx.x; i < e; i += 1024) {
    unsigned rec = sorted[i];
    int dst = (int)(rec >> 16);
    int pos = atomicAdd(&lcnt[dst & 255], 1);
    if (pos < CAP) adj[(size_t)dst * CAP + pos] = (unsigned short)(rec & 0xffffu);
  }
  __syncthreads();
  if (threadIdx.x < 256) {
    int dst = (k << 8) + threadIdx.x;
    if (dst < N_NODES)
      invd[dst] = 1.0f / (float)max(min(lcnt[threadIdx.x], CAP), 1);
  }
}

// Kernel 5: gather-mean + fused output matmuls. 512 threads = 8 waves; each
// wave owns TWO nodes. adj rows are blind-loaded (dummy-padded), so the
// critical path is adj -> shfl -> row loads (2 round trips, not 3). Degree
// decisions come from __ballot; mean scale from precomputed invd.
__global__ __launch_bounds__(512, 6) void k_gather_out(
    const f16x2* __restrict__ hf2, const float* __restrict__ invd,
    const unsigned short* __restrict__ adj, const f16x2* __restrict__ wf16,
    const float* __restrict__ bl, float* __restrict__ out) {
  __shared__ f16x2 sWl2[D][34];
  __shared__ f16x2 sWr2[D][34];
  __shared__ f16x2 sA2[16][32];
  __shared__ f16x2 sH2[16][32];
  int w = threadIdx.x >> 6;
  int L = threadIdx.x & 63;
  {
    int i0 = threadIdx.x * 4;  // 4 consecutive words, same row
    int row = i0 >> 5, col = i0 & 31;
    const f16x2* wl = wf16;
    const f16x2* wr = wf16 + 2048;
#pragma unroll
    for (int j = 0; j < 4; ++j) {
      sWl2[row][col + j] = wl[i0 + j];
      sWr2[row][col + j] = wr[i0 + j];
    }
  }
  __syncthreads();

  int nA = blockIdx.x * 16 + w * 2;  // 50000 % 16 == 0
  int nB = nA + 1;
  int abA = nA * CAP, abB = nB * CAP;
  // independent loads, one round trip
  int myA = (int)__builtin_nontemporal_load(adj + abA + L);
  int myB = (int)__builtin_nontemporal_load(adj + abB + L);
  float invA = __builtin_nontemporal_load(invd + nA);
  float invB = __builtin_nontemporal_load(invd + nB);

  unsigned long long bm =
      __ballot(myA != DUMMY) | __ballot(myB != DUMMY);

  int o = L >> 3;
  int c8 = L & 7;
  int coff = c8 << 4;
  const char* hb = (const char*)hf2;

  f16x2 aA[4], aB[4];
#pragma unroll
  for (int t = 0; t < 4; ++t) {
    aA[t] = __builtin_bit_cast(f16x2, 0u);
    aB[t] = __builtin_bit_cast(f16x2, 0u);
  }
  gpair(myA, myB, 0, o, hb, coff, aA, aB);                 // slots 0-31
  if ((bm >> 32) != 0ull) gpair(myA, myB, 32, o, hb, coff, aA, aB);  // 32-63
  if ((bm >> 63) != 0ull) {  // rare: deg >= 64 -> slots 64-95 (dummy-padded)
    int myA2 = (L < 32) ? (int)__builtin_nontemporal_load(adj + abA + 64 + L)
                        : DUMMY;
    int myB2 = (L < 32) ? (int)__builtin_nontemporal_load(adj + abB + 64 + L)
                        : DUMMY;
    gpair(myA2, myB2, 0, o, hb, coff, aA, aB);
  }

  // combine the 8 lane-octants (bits 3,4,5 of L), packed f16
#pragma unroll
  for (int msk = 8; msk <= 32; msk <<= 1) {
#pragma unroll
    for (int t = 0; t < 4; ++t) {
      aA[t] += shflx2(aA[t], msk);
      aB[t] += shflx2(aB[t], msk);
    }
  }
  if (o == 0) {  // lane c8 owns features 8c8..8c8+7 of node A
#pragma unroll
    for (int t = 0; t < 4; ++t) {
      f16x2 p;
      p.x = (_Float16)((float)aA[t].x * invA);
      p.y = (_Float16)((float)aA[t].y * invA);
      sA2[2 * w][4 * c8 + t] = p;
    }
  } else if (o == 1) {  // node B (sums replicated across octants)
#pragma unroll
    for (int t = 0; t < 4; ++t) {
      f16x2 p;
      p.x = (_Float16)((float)aB[t].x * invB);
      p.y = (_Float16)((float)aB[t].y * invB);
      sA2[2 * w + 1][4 * c8 + t] = p;
    }
  }
  if (L < 32) sH2[2 * w][L] = hf2[(size_t)nA * 32 + L];
  else sH2[2 * w + 1][L - 32] = hf2[(size_t)nB * 32 + (L - 32)];

  float accA = bl[L];  // wave-private sA2/sH2: in-wave lgkmcnt ordering
  float accB = accA;
#pragma unroll
  for (int k2 = 0; k2 < 32; ++k2) {
    f16x2 wlv = sWl2[L][k2];
    f16x2 wrv = sWr2[L][k2];
    accA = dot2acc(sA2[2 * w][k2], wlv, accA);
    accA = dot2acc(sH2[2 * w][k2], wrv, accA);
    accB = dot2acc(sA2[2 * w + 1][k2], wlv, accB);
    accB = dot2acc(sH2[2 * w + 1][k2], wrv, accB);
  }
  __builtin_nontemporal_store(accA, out + (size_t)nA * D + L);
  __builtin_nontemporal_store(accB, out + (size_t)nB * D + L);
}

extern "C" void kernel_launch(void* const* d_in, const int* in_sizes, int n_in,
                              void* d_out, int out_size, void* d_ws,
                              size_t ws_size, hipStream_t stream) {
  const float* x = (const float*)d_in[0];
  const float* mask = (const float*)d_in[1];
  const float* gamma = (const float*)d_in[2];
  const float* beta = (const float*)d_in[3];
  const float* Wl = (const float*)d_in[4];
  const float* bl = (const float*)d_in[5];
  const float* Wr = (const float*)d_in[6];
  const int* ei = (const int*)d_in[7];
  float* out = (float*)d_out;

  // ws layout (~25.3 MB)
  f16x2* hf2 = (f16x2*)d_ws;                           // 65536*128 B = 8.39 MB
  unsigned* sorted = (unsigned*)(hf2 + (size_t)NROWS * 32);  // 6.4 MB
  int* ghistT = (int*)(sorted + (size_t)N_EDGES);      // 0.31 MB
  int* chunkbaseT = ghistT + NBUCK * NCHUNK;           // 0.31 MB
  int* total = chunkbaseT + NBUCK * NCHUNK;            // 0.8 KB
  int* bucket_start = total + NBUCK;                   // 0.8 KB
  float* invd = (float*)(bucket_start + (NBUCK + 2));  // 0.2 MB
  unsigned short* adj = (unsigned short*)(invd + N_NODES);  // 9.6 MB
  f16x2* wf16 = (f16x2*)(adj + (size_t)N_NODES * CAP);      // 16 KB

  dim3 blk(256);
  k_front<<<G_FILL0 + FILLB, blk, 0, stream>>>(x, mask, gamma, beta, hf2, ei,
                                               ghistT, (uint4*)adj);
  k_scan1<<<NBUCK, blk, 0, stream>>>(ghistT, chunkbaseT, total);
  k_scan2<<<17, blk, 0, stream>>>(total, bucket_start, Wl, Wr, wf16);
  k_scatter2<<<NCHUNK, dim3(512), 0, stream>>>(ei, chunkbaseT, bucket_start,
                                               sorted);
  k_place3<<<NBUCK, dim3(1024), 0, stream>>>(sorted, bucket_start, adj, invd);
  k_gather_out<<<N_NODES / 16, dim3(512), 0, stream>>>(hf2, invd, adj, wf16,
                                                       bl, out);
}